// Round 1
// baseline (484.229 us; speedup 1.0000x reference)
//
#include <hip/hip_runtime.h>
#include <hip/hip_bf16.h>

#define BB 8
#define CC 256
#define HH 128
#define WW 128

typedef __attribute__((ext_vector_type(8))) short bf16x8;
typedef __attribute__((ext_vector_type(4))) float f32x4;

// fp32 -> bf16 round-to-nearest-even (bit trick; inputs are finite)
static __device__ __forceinline__ unsigned short f2bf(float f) {
  unsigned int u = __builtin_bit_cast(unsigned int, f);
  u += 0x7fffu + ((u >> 16) & 1u);
  return (unsigned short)(u >> 16);
}

// async 16B global->LDS (one global_load_lds_dwordx4 per wave).
// LDS dest must equal wave-uniform base + lane*16 — callers guarantee this.
static __device__ __forceinline__ void async16(const void* g, void* l) {
#if __has_builtin(__builtin_amdgcn_global_load_lds)
  __builtin_amdgcn_global_load_lds(
      (__attribute__((address_space(1))) void*)(unsigned long long)(g),
      (__attribute__((address_space(3))) void*)(unsigned int)(unsigned long long)(l),
      16, 0, 0);
#else
  *(bf16x8*)l = *(const bf16x8*)g;
#endif
}

// ---------------------------------------------------------------------------
// Kernel 1: w_deform [co][ci][kh][kw] fp32 -> Wt [co][tap][ci] bf16
// ---------------------------------------------------------------------------
__global__ __launch_bounds__(256) void k_convert_w(const float* __restrict__ w,
                                                   unsigned short* __restrict__ Wt) {
  const int idx = blockIdx.x * 256 + threadIdx.x;  // < 256*9*256 = 589824
  const int co = idx / 2304;
  const int r = idx - co * 2304;
  const int tap = r >> 8, ci = r & 255;
  Wt[idx] = f2bf(w[(co * CC + ci) * 9 + tap]);
}

// ---------------------------------------------------------------------------
// Kernel 2: x [b][c][h][w] fp32 -> Xc [b][h][w][c] bf16 (LDS-tiled transpose)
// ---------------------------------------------------------------------------
__global__ __launch_bounds__(256) void k_transpose_x(const float* __restrict__ x,
                                                     unsigned short* __restrict__ Xc) {
  __shared__ float tile[64][65];
  const int t = threadIdx.x;
  const int bz = blockIdx.z;
  const int b = bz >> 7, h = bz & 127;
  const int c0 = blockIdx.y << 6, w0 = blockIdx.x << 6;
  const float* xp = x + (((b * CC) * HH) + h) * WW;  // x[b][0][h][0]
#pragma unroll
  for (int i = 0; i < 4; ++i) {
    int idx = t + (i << 8);
    int cr = idx >> 4, wq = idx & 15;
    float4 v = *(const float4*)(xp + (c0 + cr) * (HH * WW) + w0 + (wq << 2));
    tile[cr][(wq << 2) + 0] = v.x;
    tile[cr][(wq << 2) + 1] = v.y;
    tile[cr][(wq << 2) + 2] = v.z;
    tile[cr][(wq << 2) + 3] = v.w;
  }
  __syncthreads();
#pragma unroll
  for (int i = 0; i < 4; ++i) {
    int idx = t + (i << 8);
    int wr = idx >> 4, cq = idx & 15;
    ushort4 o;
    o.x = f2bf(tile[(cq << 2) + 0][wr]);
    o.y = f2bf(tile[(cq << 2) + 1][wr]);
    o.z = f2bf(tile[(cq << 2) + 2][wr]);
    o.w = f2bf(tile[(cq << 2) + 3][wr]);
    *(ushort4*)(Xc + ((((b * HH) + h) * WW) + w0 + wr) * CC + c0 + (cq << 2)) = o;
  }
}

// ---------------------------------------------------------------------------
// Kernel 3: implicit-GEMM conv via MFMA bf16. Block = 128 c_out x one W row.
// K order: tap-major, c_in-minor (chunks of 32). Epilogue: +bias, store y,
// and atomicAdd per-(b,c_out) row sums into pool for the SE global mean.
// ---------------------------------------------------------------------------
__global__ __launch_bounds__(256, 2) void k_conv(
    const unsigned short* __restrict__ Xc, const unsigned short* __restrict__ Wt,
    const float* __restrict__ bias, float* __restrict__ out,
    float* __restrict__ pool) {
  __shared__ __align__(16) unsigned short Aw[2][128 * 32];  // [dbuf][m][c] 16 KB
  __shared__ __align__(16) unsigned short Xs[3 * 130 * 32]; // [dh][wp][c] 25 KB
  const int t = threadIdx.x;
  const int m0 = blockIdx.x << 7;          // c_out tile base (0 or 128)
  const int bh = blockIdx.y;
  const int b = bh >> 7, h = bh & 127;
  const int lane = t & 63, wid = t >> 6;
  const int wave_m = (wid & 1) << 6, wave_n = (wid >> 1) << 6;
  const int n0 = lane & 15, quad = lane >> 4;

  // zero halo columns (wp=0 and wp=129) once; staging never touches them
  if (t < 192) {
    int dh = t >> 6;
    int rem = t & 63;
    Xs[dh * 4160 + ((rem >> 5) ? (129 * 32) : 0) + (rem & 31)] = 0;
  }
  // out-of-image rows stay all-zero (loads for them are skipped every chunk)
  if (h == 0)   { for (int i = t; i < 4160; i += 256) Xs[i] = 0; }
  if (h == 127) { for (int i = t; i < 4160; i += 256) Xs[2 * 4160 + i] = 0; }

  f32x4 zero4 = {0.f, 0.f, 0.f, 0.f};
  f32x4 acc[4][4];
#pragma unroll
  for (int i = 0; i < 4; ++i)
#pragma unroll
    for (int j = 0; j < 4; ++j) acc[i][j] = zero4;

  const int e0 = t << 3;        // this thread's 8-elem (16B) staging slot, call 0
  const int e1 = e0 + 2048;     // call 1
  const int xm0 = e0 >> 5, xc0 = e0 & 31;
  const int xm1 = e1 >> 5, xc1 = e1 & 31;

  for (int cb = 0; cb < 256; cb += 32) {   // c_in chunk
    // stage Xs: 3 rows x 128 wp x 32 c of Xc (bf16), async direct-to-LDS
#pragma unroll
    for (int dh = 0; dh < 3; ++dh) {
      const int hh = h - 1 + dh;
      if (hh >= 0 && hh < HH) {
        const unsigned short* gb = Xc + (((b * HH) + hh) * WW) * CC + cb;
        async16(gb + xm0 * CC + xc0, &Xs[dh * 4160 + 32 + e0]);
        async16(gb + xm1 * CC + xc1, &Xs[dh * 4160 + 32 + e1]);
      }
    }
    // stage A-tile for tap 0 into buffer 0
    {
      const unsigned short* gw = Wt + cb;
      async16(gw + (m0 + xm0) * 2304 + xc0, &Aw[0][e0]);
      async16(gw + (m0 + xm1) * 2304 + xc1, &Aw[0][e1]);
    }
    __syncthreads();
#pragma unroll
    for (int tap = 0; tap < 9; ++tap) {
      const int cur = tap & 1;
      if (tap < 8) {  // prefetch next tap's A-tile into the other buffer
        const unsigned short* gw = Wt + (tap + 1) * 256 + cb;
        async16(gw + (m0 + xm0) * 2304 + xc0, &Aw[cur ^ 1][e0]);
        async16(gw + (m0 + xm1) * 2304 + xc1, &Aw[cur ^ 1][e1]);
      }
      const int kh = tap / 3, kw = tap % 3;
      bf16x8 af[4], bg[4];
#pragma unroll
      for (int i = 0; i < 4; ++i)   // A[m=lane&15][k=quad*8+j]
        af[i] = *(const bf16x8*)&Aw[cur][(wave_m + (i << 4) + n0) * 32 + (quad << 3)];
#pragma unroll
      for (int j = 0; j < 4; ++j)   // B[k=quad*8+j][n=lane&15]; wp = n + kw
        bg[j] = *(const bf16x8*)&Xs[kh * 4160 + (wave_n + (j << 4) + n0 + kw) * 32 + (quad << 3)];
#pragma unroll
      for (int i = 0; i < 4; ++i)
#pragma unroll
        for (int j = 0; j < 4; ++j)
          acc[i][j] = __builtin_amdgcn_mfma_f32_16x16x32_bf16(af[i], bg[j], acc[i][j], 0, 0, 0);
      __syncthreads();
    }
  }

  // epilogue: D col = lane&15 (w), row = quad*4 + reg (c_out)
#pragma unroll
  for (int i = 0; i < 4; ++i) {
    const int mrow = m0 + wave_m + (i << 4) + (quad << 2);
    float bv[4];
#pragma unroll
    for (int r = 0; r < 4; ++r) bv[r] = bias[mrow + r];
    float psum[4] = {0.f, 0.f, 0.f, 0.f};
#pragma unroll
    for (int j = 0; j < 4; ++j) {
      const int wcol = wave_n + (j << 4) + n0;
      float* op = out + (((b * CC) + mrow) * HH + h) * WW + wcol;
#pragma unroll
      for (int r = 0; r < 4; ++r) {
        float v = acc[i][j][r] + bv[r];
        op[r * (HH * WW)] = v;
        psum[r] += v;
      }
    }
#pragma unroll
    for (int r = 0; r < 4; ++r) {
      float s = psum[r];
      s += __shfl_xor(s, 1, 16);
      s += __shfl_xor(s, 2, 16);
      s += __shfl_xor(s, 4, 16);
      s += __shfl_xor(s, 8, 16);
      if (n0 == 0) atomicAdd(&pool[b * CC + mrow + r], s);
    }
  }
}

// ---------------------------------------------------------------------------
// Kernel 4: SE head. One block per batch. scale = sigmoid(W2 relu(W1 p + b1) + b2)
// ---------------------------------------------------------------------------
__global__ __launch_bounds__(256) void k_se(const float* __restrict__ pool,
                                            const float* __restrict__ w1,
                                            const float* __restrict__ b1,
                                            const float* __restrict__ w2,
                                            const float* __restrict__ b2,
                                            float* __restrict__ scale) {
  __shared__ float p[CC];
  __shared__ float h1[64];
  const int b = blockIdx.x, t = threadIdx.x;
  p[t] = pool[b * CC + t] * (1.0f / 16384.0f);
  __syncthreads();
  if (t < 64) {
    float s = b1[t];
    const float* wr = w1 + t * CC;
    for (int c = 0; c < CC; ++c) s += wr[c] * p[c];
    h1[t] = s > 0.f ? s : 0.f;
  }
  __syncthreads();
  float s = b2[t];
  const float* wr = w2 + t * 64;
#pragma unroll
  for (int k = 0; k < 64; ++k) s += wr[k] * h1[k];
  scale[b * CC + t] = 1.0f / (1.0f + expf(-s));
}

// ---------------------------------------------------------------------------
// Kernel 5: out *= scale[b][c], float4 grid-stride-free (exact-size grid)
// ---------------------------------------------------------------------------
__global__ __launch_bounds__(256) void k_scale(float* __restrict__ out,
                                               const float* __restrict__ scale) {
  const int i4 = blockIdx.x * 256 + threadIdx.x;   // 8388608 float4s
  const float s = scale[i4 >> 12];                 // 4096 float4 per (b,c) plane
  float4* p = (float4*)out + i4;
  float4 v = *p;
  v.x *= s; v.y *= s; v.z *= s; v.w *= s;
  *p = v;
}

extern "C" void kernel_launch(void* const* d_in, const int* in_sizes, int n_in,
                              void* d_out, int out_size, void* d_ws, size_t ws_size,
                              hipStream_t stream) {
  const float* x  = (const float*)d_in[0];
  const float* wd = (const float*)d_in[1];
  const float* bd = (const float*)d_in[2];
  const float* w1 = (const float*)d_in[3];
  const float* b1 = (const float*)d_in[4];
  const float* w2 = (const float*)d_in[5];
  const float* b2 = (const float*)d_in[6];
  float* out = (float*)d_out;

  // workspace layout (65.2 MiB total)
  char* ws = (char*)d_ws;
  unsigned short* Xc = (unsigned short*)ws;                        // 67108864 B
  unsigned short* Wt = (unsigned short*)(ws + 67108864);           //  1179648 B
  float* pool  = (float*)(ws + 67108864 + 1179648);                //     8192 B
  float* scale = (float*)(ws + 67108864 + 1179648 + 8192);         //     8192 B

  hipMemsetAsync(pool, 0, BB * CC * sizeof(float), stream);
  k_convert_w<<<dim3(2304), dim3(256), 0, stream>>>(wd, Wt);
  k_transpose_x<<<dim3(2, 4, 1024), dim3(256), 0, stream>>>(x, Xc);
  k_conv<<<dim3(2, 1024), dim3(256), 0, stream>>>(Xc, Wt, bd, out, pool);
  k_se<<<dim3(8), dim3(256), 0, stream>>>(pool, w1, b1, w2, b2, scale);
  k_scale<<<dim3(32768), dim3(256), 0, stream>>>(out, scale);
}